// Round 1
// baseline (1017.907 us; speedup 1.0000x reference)
//
#include <hip/hip_runtime.h>

// Problem constants (from reference): B,S,H,D = 2,4096,32,128; K=256 clusters.
constexpr int D = 128;
constexpr int K = 256;
constexpr float LR = 0.01f;

// ---------------- zero ws ----------------
__global__ __launch_bounds__(256) void k_zero(float* ws, int n) {
  int i = blockIdx.x * 256 + threadIdx.x;
  if (i < n) ws[i] = 0.0f;
}

// ---------------- centroid squared norms ----------------
__global__ __launch_bounds__(64) void k_cnorm(const float* __restrict__ cent,
                                              float* __restrict__ cnorm) {
  int c = blockIdx.x, t = threadIdx.x;
  float x0 = cent[c * D + t];
  float x1 = cent[c * D + t + 64];
  float s = x0 * x0 + x1 * x1;
#pragma unroll
  for (int off = 32; off; off >>= 1) s += __shfl_down(s, off, 64);
  if (t == 0) cnorm[c] = s;
}

// ---------------- assignment: argmin_c ||k - c||^2 = argmin_c (||c||^2 - 2 k.c) ----
// One thread per point; the 128-float key lives in 32 float4 VGPRs.
// Centroid loads are wave-uniform (scalar-load friendly, L2-resident 128 KiB).
__global__ __launch_bounds__(256, 1) void k_assign(
    const float* __restrict__ keys, const float* __restrict__ cent,
    const float* __restrict__ cnorm, float* __restrict__ out_idx,
    unsigned int* __restrict__ counts) {
  const int pid = blockIdx.x * 256 + threadIdx.x;

  float4 kr[32];
  const float4* kp = reinterpret_cast<const float4*>(keys) + (size_t)pid * 32;
#pragma unroll
  for (int i = 0; i < 32; i++) kr[i] = kp[i];

  const float4* cp = reinterpret_cast<const float4*>(cent);
  float best = 3.0e38f;
  int bc = 0;
  for (int c = 0; c < K; c++) {
    float a0 = 0.f, a1 = 0.f, a2 = 0.f, a3 = 0.f;
#pragma unroll
    for (int i = 0; i < 32; i++) {
      float4 cv = cp[c * 32 + i];
      a0 = fmaf(kr[i].x, cv.x, a0);
      a1 = fmaf(kr[i].y, cv.y, a1);
      a2 = fmaf(kr[i].z, cv.z, a2);
      a3 = fmaf(kr[i].w, cv.w, a3);
    }
    float dist = cnorm[c] - 2.0f * ((a0 + a1) + (a2 + a3));
    if (dist < best) { best = dist; bc = c; }  // strict <: first-min tie-break
  }

  out_idx[pid] = (float)bc;

  // per-block histogram -> global counts
  __shared__ unsigned int hist[K];
  hist[threadIdx.x] = 0u;
  __syncthreads();
  atomicAdd(&hist[bc], 1u);
  __syncthreads();
  unsigned int h = hist[threadIdx.x];
  if (h) atomicAdd(&counts[threadIdx.x], h);
}

// ---------------- segment sums: LDS accumulate (ds_add_f32), then global atomics ----
__global__ __launch_bounds__(256) void k_sum(const float* __restrict__ src,
                                             const float* __restrict__ idxf,
                                             float* __restrict__ gacc, int pts) {
  __shared__ float acc[K * D];  // 128 KiB (gfx950 LDS = 160 KiB)
  for (int i = threadIdx.x; i < K * D; i += 256) acc[i] = 0.f;
  __syncthreads();

  const int half = threadIdx.x >> 7;  // two points per iteration
  const int d = threadIdx.x & 127;
  const int base = blockIdx.x * pts;

#pragma unroll 4
  for (int p = 0; p < pts; p += 2) {
    int point = base + p + half;
    int c = (int)idxf[point];
    float v = src[(size_t)point * D + d];
    atomicAdd(&acc[(c << 7) + d], v);  // ds_add_f32, fire-and-forget
  }
  __syncthreads();

  for (int i = threadIdx.x; i < K * D; i += 256) {
    atomicAdd(&gacc[i], acc[i]);
  }
}

// ---------------- EMA update + counts output ----------------
__global__ __launch_bounds__(128) void k_update(
    const float* __restrict__ kc, const float* __restrict__ vc,
    const float* __restrict__ oldcnt, const unsigned int* __restrict__ counts,
    const float* __restrict__ ksum, const float* __restrict__ vsum,
    float* __restrict__ out_kc, float* __restrict__ out_vc,
    float* __restrict__ out_cnt) {
  int c = blockIdx.x, t = threadIdx.x;
  float cnt = (float)counts[c];
  float safe = fmaxf(cnt, 1.0f);
  float km = ksum[c * D + t] / safe;
  float vm = vsum[c * D + t] / safe;
  float okc = kc[c * D + t], ovc = vc[c * D + t];
  bool ne = cnt > 0.0f;
  out_kc[c * D + t] = ne ? (1.0f - LR) * okc + LR * km : okc;
  out_vc[c * D + t] = ne ? (1.0f - LR) * ovc + LR * vm : ovc;
  if (t == 0) out_cnt[c] = oldcnt[c] + cnt;
}

extern "C" void kernel_launch(void* const* d_in, const int* in_sizes, int n_in,
                              void* d_out, int out_size, void* d_ws, size_t ws_size,
                              hipStream_t stream) {
  const float* keys = (const float*)d_in[0];
  const float* values = (const float*)d_in[1];
  const float* kcent = (const float*)d_in[2];
  const float* vcent = (const float*)d_in[3];
  const float* oldcnt = (const float*)d_in[4];
  const int N = in_sizes[0] / D;  // 262144

  float* ws = (float*)d_ws;
  unsigned int* w_counts = (unsigned int*)ws;  // 256 (zeroed as float 0 == u32 0)
  float* w_cnorm = ws + 256;                   // 256
  float* w_ksum = ws + 512;                    // 32768
  float* w_vsum = ws + 512 + K * D;            // 32768

  float* o_idx = (float*)d_out;       // N
  float* o_kc = o_idx + N;            // K*D
  float* o_vc = o_kc + K * D;         // K*D
  float* o_cnt = o_vc + K * D;        // K

  int zn = 512 + 2 * K * D;
  k_zero<<<(zn + 255) / 256, 256, 0, stream>>>(ws, zn);
  k_cnorm<<<K, 64, 0, stream>>>(kcent, w_cnorm);
  k_assign<<<N / 256, 256, 0, stream>>>(keys, kcent, w_cnorm, o_idx, w_counts);
  int pts = N / 256;  // 1024 points per block
  k_sum<<<256, 256, 0, stream>>>(keys, o_idx, w_ksum, pts);
  k_sum<<<256, 256, 0, stream>>>(values, o_idx, w_vsum, pts);
  k_update<<<K, D, 0, stream>>>(kcent, vcent, oldcnt, w_counts, w_ksum, w_vsum,
                                o_kc, o_vc, o_cnt);
}

// Round 2
// 819.819 us; speedup vs baseline: 1.2416x; 1.2416x over previous
//
#include <hip/hip_runtime.h>

constexpr int D = 128;
constexpr int K = 256;
constexpr float LR = 0.01f;
constexpr int BM = 128;   // points per block in assign
constexpr int BK = 32;    // reduce-dim step

// ---------------- zero ----------------
__global__ __launch_bounds__(256) void k_zero(float* p, int n) {
  int i = blockIdx.x * 256 + threadIdx.x;
  if (i < n) p[i] = 0.0f;
}

// ---------------- prep: centT[d][c] = cent[c][d], cnorm[c] = ||c||^2 ----------------
__global__ __launch_bounds__(128) void k_prep(const float* __restrict__ cent,
                                              float* __restrict__ centT,
                                              float* __restrict__ cnorm) {
  int c = blockIdx.x, t = threadIdx.x;
  float v = cent[c * D + t];
  centT[t * K + c] = v;
  float s = v * v;
#pragma unroll
  for (int off = 32; off; off >>= 1) s += __shfl_down(s, off, 64);
  __shared__ float w0;
  if (t == 0) w0 = s;
  __syncthreads();
  if (t == 64) cnorm[c] = w0 + s;
}

// ---------------- assignment: tiled fp32 GEMM + argmin epilogue ----------------
// Block: 128 points x all 256 clusters. 256 threads, per-thread tile 8x16.
__global__ __launch_bounds__(256, 2) void k_assign(
    const float* __restrict__ keys, const float* __restrict__ centT,
    const float* __restrict__ cnorm, float* __restrict__ out_idx,
    unsigned int* __restrict__ counts) {
  // B row layout: cluster group g (16 clusters) at word offset g*20 (stride 20
  // -> 2-way bank alias across the 16 tx groups = free; 16B aligned).
  __shared__ float As[BK][BM];        // 16 KB
  __shared__ float Bs[BK][16 * 20];   // 40 KB
  __shared__ float sd[BM][17];        // 8.7 KB
  __shared__ int si[BM][17];          // 8.7 KB
  __shared__ unsigned int hist[K];    // 1 KB   (total ~75.7 KB -> 2 blocks/CU)

  const int tid = threadIdx.x;
  const int tx = tid & 15;   // cluster group: clusters tx*16 .. tx*16+15
  const int ty = tid >> 4;   // point group: points ty*8 .. ty*8+7
  const size_t bm = (size_t)blockIdx.x * BM;

  float4 acc[8][4];
#pragma unroll
  for (int i = 0; i < 8; i++)
#pragma unroll
    for (int j = 0; j < 4; j++) acc[i][j] = make_float4(0.f, 0.f, 0.f, 0.f);

  // staging decomposition
  const int sm = tid & 127;         // A: point
  const int skh = tid >> 7;         // A: k-half (16 floats)
  const int sc4 = (tid & 63) * 4;   // B: 4 consecutive clusters
  const int skq = tid >> 6;         // B: k-quarter (8 rows)
  const int bcol = ((sc4 >> 4) * 20) + (sc4 & 15);

  for (int kt = 0; kt < D; kt += BK) {
    // stage A (transpose): As[k][m] = keys[bm+m][kt+k]
    {
      const float4* src =
          reinterpret_cast<const float4*>(keys + (bm + sm) * D + kt + skh * 16);
      float4 v0 = src[0], v1 = src[1], v2 = src[2], v3 = src[3];
      int kb = skh * 16;
      As[kb + 0][sm] = v0.x;  As[kb + 1][sm] = v0.y;
      As[kb + 2][sm] = v0.z;  As[kb + 3][sm] = v0.w;
      As[kb + 4][sm] = v1.x;  As[kb + 5][sm] = v1.y;
      As[kb + 6][sm] = v1.z;  As[kb + 7][sm] = v1.w;
      As[kb + 8][sm] = v2.x;  As[kb + 9][sm] = v2.y;
      As[kb + 10][sm] = v2.z; As[kb + 11][sm] = v2.w;
      As[kb + 12][sm] = v3.x; As[kb + 13][sm] = v3.y;
      As[kb + 14][sm] = v3.z; As[kb + 15][sm] = v3.w;
    }
    // stage B: Bs[k][col(c)] = centT[kt+k][c]
    {
#pragma unroll
      for (int j = 0; j < 8; j++) {
        int k = skq * 8 + j;
        float4 v = *reinterpret_cast<const float4*>(centT + (size_t)(kt + k) * K + sc4);
        *reinterpret_cast<float4*>(&Bs[k][bcol]) = v;
      }
    }
    __syncthreads();

#pragma unroll
    for (int kk = 0; kk < BK; kk++) {
      const float4* Ap = reinterpret_cast<const float4*>(&As[kk][ty * 8]);
      float4 a0 = Ap[0], a1 = Ap[1];
      const float4* Bp = reinterpret_cast<const float4*>(&Bs[kk][tx * 20]);
      float4 b0 = Bp[0], b1 = Bp[1], b2 = Bp[2], b3 = Bp[3];
      float a[8] = {a0.x, a0.y, a0.z, a0.w, a1.x, a1.y, a1.z, a1.w};
#pragma unroll
      for (int i = 0; i < 8; i++) {
        acc[i][0].x = fmaf(a[i], b0.x, acc[i][0].x);
        acc[i][0].y = fmaf(a[i], b0.y, acc[i][0].y);
        acc[i][0].z = fmaf(a[i], b0.z, acc[i][0].z);
        acc[i][0].w = fmaf(a[i], b0.w, acc[i][0].w);
        acc[i][1].x = fmaf(a[i], b1.x, acc[i][1].x);
        acc[i][1].y = fmaf(a[i], b1.y, acc[i][1].y);
        acc[i][1].z = fmaf(a[i], b1.z, acc[i][1].z);
        acc[i][1].w = fmaf(a[i], b1.w, acc[i][1].w);
        acc[i][2].x = fmaf(a[i], b2.x, acc[i][2].x);
        acc[i][2].y = fmaf(a[i], b2.y, acc[i][2].y);
        acc[i][2].z = fmaf(a[i], b2.z, acc[i][2].z);
        acc[i][2].w = fmaf(a[i], b2.w, acc[i][2].w);
        acc[i][3].x = fmaf(a[i], b3.x, acc[i][3].x);
        acc[i][3].y = fmaf(a[i], b3.y, acc[i][3].y);
        acc[i][3].z = fmaf(a[i], b3.z, acc[i][3].z);
        acc[i][3].w = fmaf(a[i], b3.w, acc[i][3].w);
      }
    }
    __syncthreads();
  }

  // epilogue: dist = cnorm[c] - 2*dot; local argmin over this thread's 16 clusters
  float cn[16];
#pragma unroll
  for (int j = 0; j < 16; j++) cn[j] = cnorm[tx * 16 + j];

#pragma unroll
  for (int i = 0; i < 8; i++) {
    float bd = 3.0e38f;
    int bi = 0;
    const float* av = reinterpret_cast<const float*>(&acc[i][0]);
#pragma unroll
    for (int j = 0; j < 16; j++) {
      float d2 = cn[j] - 2.0f * av[j];
      if (d2 < bd) { bd = d2; bi = tx * 16 + j; }
    }
    sd[ty * 8 + i][tx] = bd;
    si[ty * 8 + i][tx] = bi;
  }
  hist[tid] = 0u;
  __syncthreads();

  if (tid < BM) {
    float bd = sd[tid][0];
    int bi = si[tid][0];
#pragma unroll
    for (int t = 1; t < 16; t++) {
      float dv = sd[tid][t];
      int iv = si[tid][t];
      if (dv < bd || (dv == bd && iv < bi)) { bd = dv; bi = iv; }
    }
    out_idx[bm + tid] = (float)bi;
    atomicAdd(&hist[bi], 1u);
  }
  __syncthreads();
  unsigned int h = hist[tid];
  if (h) atomicAdd(&counts[tid], h);
}

// ---------------- segment-sum phase A: per-block LDS accumulate ----------------
__global__ __launch_bounds__(1024) void k_psum(const float* __restrict__ src,
                                               const float* __restrict__ idxf,
                                               float* __restrict__ out, int ppb,
                                               int partial) {
  __shared__ float acc[K * D];  // 128 KB
  for (int i = threadIdx.x; i < K * D; i += 1024) acc[i] = 0.f;
  __syncthreads();

  const int d = threadIdx.x & 127;
  const int ps = threadIdx.x >> 7;  // 8 points in flight
  const int base = blockIdx.x * ppb;

#pragma unroll 4
  for (int p = ps; p < ppb; p += 8) {
    int c = (int)idxf[base + p];
    float v = src[(size_t)(base + p) * D + d];
    atomicAdd(&acc[(c << 7) + d], v);  // ds_add_f32; wave-uniform c -> conflict-free
  }
  __syncthreads();

  if (partial) {
    float* o = out + (size_t)blockIdx.x * (K * D);
    for (int i = threadIdx.x; i < K * D; i += 1024) o[i] = acc[i];
  } else {
    for (int i = threadIdx.x; i < K * D; i += 1024) {
      float v = acc[i];
      if (v != 0.f) atomicAdd(&out[i], v);
    }
  }
}

// ---------------- reduce partials + EMA update + counts ----------------
__global__ __launch_bounds__(256) void k_finish(
    const float* __restrict__ pk, const float* __restrict__ pv, int nb,
    const float* __restrict__ kc, const float* __restrict__ vc,
    const float* __restrict__ oldcnt, const unsigned int* __restrict__ counts,
    float* __restrict__ ok, float* __restrict__ ov, float* __restrict__ ocnt) {
  int i = blockIdx.x * 256 + threadIdx.x;  // 0..K*D-1
  int c = i >> 7;
  float sk = 0.f, sv = 0.f;
#pragma unroll 8
  for (int b = 0; b < nb; b++) {
    sk += pk[(size_t)b * (K * D) + i];
    sv += pv[(size_t)b * (K * D) + i];
  }
  float cnt = (float)counts[c];
  float safe = fmaxf(cnt, 1.0f);
  float km = sk / safe, vm = sv / safe;
  float okc = kc[i], ovc = vc[i];
  bool ne = cnt > 0.f;
  ok[i] = ne ? (1.0f - LR) * okc + LR * km : okc;
  ov[i] = ne ? (1.0f - LR) * ovc + LR * vm : ovc;
  if ((i & 127) == 0) ocnt[c] = oldcnt[c] + cnt;
}

extern "C" void kernel_launch(void* const* d_in, const int* in_sizes, int n_in,
                              void* d_out, int out_size, void* d_ws, size_t ws_size,
                              hipStream_t stream) {
  const float* keys = (const float*)d_in[0];
  const float* values = (const float*)d_in[1];
  const float* kcent = (const float*)d_in[2];
  const float* vcent = (const float*)d_in[3];
  const float* oldcnt = (const float*)d_in[4];
  const int N = in_sizes[0] / D;  // 262144

  float* ws = (float*)d_ws;
  unsigned int* w_counts = (unsigned int*)ws;  // 256
  float* w_centT = ws + 256;                   // 32768
  float* w_cnorm = ws + 256 + K * D;           // 256
  float* w_pk = ws + 33280;                    // partials / sums

  float* o_idx = (float*)d_out;  // N
  float* o_kc = o_idx + N;       // K*D
  float* o_vc = o_kc + K * D;    // K*D
  float* o_cnt = o_vc + K * D;   // K

  const int NB = 256;  // partial buffers
  size_t need = (33280 + (size_t)2 * NB * K * D) * sizeof(float);
  bool partial = ws_size >= need;
  int nb = partial ? NB : 1;
  float* w_pv = w_pk + (size_t)nb * K * D;

  k_zero<<<1, 256, 0, stream>>>((float*)w_counts, 256);
  if (!partial) k_zero<<<(2 * K * D + 255) / 256, 256, 0, stream>>>(w_pk, 2 * K * D);
  k_prep<<<K, 128, 0, stream>>>(kcent, w_centT, w_cnorm);
  k_assign<<<N / BM, 256, 0, stream>>>(keys, w_centT, w_cnorm, o_idx, w_counts);
  int ppb = N / NB;  // 1024 points per block
  k_psum<<<NB, 1024, 0, stream>>>(keys, o_idx, w_pk, ppb, partial ? 1 : 0);
  k_psum<<<NB, 1024, 0, stream>>>(values, o_idx, w_pv, ppb, partial ? 1 : 0);
  k_finish<<<(K * D) / 256, 256, 0, stream>>>(w_pk, w_pv, nb, kcent, vcent, oldcnt,
                                              w_counts, o_kc, o_vc, o_cnt);
}

// Round 3
// 472.994 us; speedup vs baseline: 2.1521x; 1.7333x over previous
//
#include <hip/hip_runtime.h>

typedef _Float16 f16x8 __attribute__((ext_vector_type(8)));
typedef float f32x16 __attribute__((ext_vector_type(16)));

constexpr int D = 128;
constexpr int K = 256;
constexpr float LR = 0.01f;
constexpr float LO_SCALE = 4096.0f;        // 2^12: lo-split prescale (avoids f16 denormals)
constexpr float LO_INV = 1.0f / 4096.0f;

// ---------------- zero ws ----------------
__global__ __launch_bounds__(256) void k_zero(float* p, int n) {
  int i = blockIdx.x * 256 + threadIdx.x;
  if (i < n) p[i] = 0.0f;
}

// ---------------- prep: split centroids (prescaled by -2) + cnorm extension ---------
// csplit layout (pre-swizzled halves): idx = s*32768 + c*128 + k, sw = idx ^ ((c&15)<<3)
// extH[c*8+0] = f16(cn); extL[c*8+{0,1}] = 4096-scaled residuals of cn.
__global__ __launch_bounds__(128) void k_prep(const float* __restrict__ cent,
                                              _Float16* __restrict__ csplit,
                                              _Float16* __restrict__ extH,
                                              _Float16* __restrict__ extL) {
  int c = blockIdx.x, k = threadIdx.x;
  float x = cent[c * D + k];
  float ca = -2.0f * x;                       // fold the -2 into the centroid
  _Float16 h = (_Float16)ca;
  float r = ca - (float)h;
  _Float16 lo = (_Float16)(r * LO_SCALE);
  int idx = c * 128 + k;
  int sw = idx ^ ((c & 15) << 3);
  csplit[sw] = h;
  csplit[32768 + sw] = lo;

  // ||c||^2 (unscaled) reduce across 128 threads
  float s = x * x;
#pragma unroll
  for (int off = 32; off; off >>= 1) s += __shfl_down(s, off, 64);
  __shared__ float w0;
  if (k == 0) w0 = s;
  __syncthreads();
  if (k == 64) {
    float cn = w0 + s;
    _Float16 c1 = (_Float16)cn;
    float rr = cn - (float)c1;
    _Float16 c2s = (_Float16)(rr * LO_SCALE);
    float rr2 = rr - (float)c2s * LO_INV;
    _Float16 c3s = (_Float16)(rr2 * LO_SCALE);
    extH[c * 8 + 0] = c1;
    extL[c * 8 + 0] = c2s;
    extL[c * 8 + 1] = c3s;
  }
  if (k >= 1 && k < 8) extH[c * 8 + k] = (_Float16)0.0f;
  if (k >= 2 && k < 8) extL[c * 8 + k] = (_Float16)0.0f;
}

// ---------------- assignment: MFMA 32x32x16 f16, centroids resident in LDS --------
// Block: 512 thr (8 waves), each wave owns 32 points. acc = cn - 2*k.c via K-extension.
__global__ __launch_bounds__(512, 2) void k_assign(
    const float* __restrict__ keys, const _Float16* __restrict__ csplit,
    const _Float16* __restrict__ extH, const _Float16* __restrict__ extL,
    float* __restrict__ out_idx, unsigned int* __restrict__ counts) {
  __shared__ __align__(16) _Float16 cs[2 * 32768];      // 128 KB: [split][c][k] swizzled
  __shared__ __align__(16) _Float16 exh[2056], exl[2056];  // +8 zero pad entry
  __shared__ unsigned int hist[K];

  const int tid = threadIdx.x;
  const int lane = tid & 63;
  const int wv = tid >> 6;
  const int col = lane & 31;   // point within wave group / n-index
  const int hl = lane >> 5;    // k-half (0: k 0-7, 1: k 8-15 of each 16-tile)

  // ---- stage LDS (L2-hot, pre-swizzled linear) ----
  {
    const float4* s4 = reinterpret_cast<const float4*>(csplit);
    float4* d4 = reinterpret_cast<float4*>(cs);
#pragma unroll
    for (int it = 0; it < 16; ++it) d4[tid + 512 * it] = s4[tid + 512 * it];
    if (tid < 256) {
      reinterpret_cast<float4*>(exh)[tid] = reinterpret_cast<const float4*>(extH)[tid];
      hist[tid] = 0u;
    } else if (tid < 512) {
      reinterpret_cast<float4*>(exl)[tid - 256] =
          reinterpret_cast<const float4*>(extL)[tid - 256];
    }
    if (tid < 8) { exh[2048 + tid] = (_Float16)0.0f; exl[2048 + tid] = (_Float16)0.0f; }
  }

  // ---- load + split this lane's key fragments (B operand) ----
  const size_t pt = (size_t)blockIdx.x * 256 + wv * 32 + col;
  const float* kp = keys + pt * D + hl * 8;
  f16x8 bh[8], bl[8];
#pragma unroll
  for (int kt = 0; kt < 8; ++kt) {
    float4 x0 = *reinterpret_cast<const float4*>(kp + kt * 16);
    float4 x1 = *reinterpret_cast<const float4*>(kp + kt * 16 + 4);
    float xs[8] = {x0.x, x0.y, x0.z, x0.w, x1.x, x1.y, x1.z, x1.w};
#pragma unroll
    for (int j = 0; j < 8; ++j) {
      float x = xs[j];
      _Float16 h = (_Float16)x;
      float r = x - (float)h;
      bh[kt][j] = h;
      bl[kt][j] = (_Float16)(r * LO_SCALE);
    }
  }

  // B-side K-extension fragment: k=128 and k=129 carry 1.0 (h=0 lanes only)
  f16x8 beh = {};
  if (hl == 0) { beh[0] = (_Float16)1.0f; beh[1] = (_Float16)1.0f; }

  __syncthreads();

  float bestd = 3.0e38f;
  int bestc = 0;

#pragma unroll
  for (int ph = 0; ph < 2; ++ph) {
    f32x16 acc[4], acc2[4];
#pragma unroll
    for (int mt = 0; mt < 4; ++mt)
#pragma unroll
      for (int r = 0; r < 16; ++r) { acc[mt][r] = 0.0f; acc2[mt][r] = 0.0f; }

#pragma unroll
    for (int kt = 0; kt < 8; ++kt) {
#pragma unroll
      for (int mt = 0; mt < 4; ++mt) {
        int c = ph * 128 + mt * 32 + col;
        int sw = (c * 128 + kt * 16 + hl * 8) ^ ((c & 15) << 3);
        f16x8 ah = *reinterpret_cast<const f16x8*>(&cs[sw]);
        f16x8 al = *reinterpret_cast<const f16x8*>(&cs[32768 + sw]);
        acc[mt] = __builtin_amdgcn_mfma_f32_32x32x16_f16(ah, bh[kt], acc[mt], 0, 0, 0);
        acc2[mt] = __builtin_amdgcn_mfma_f32_32x32x16_f16(ah, bl[kt], acc2[mt], 0, 0, 0);
        acc2[mt] = __builtin_amdgcn_mfma_f32_32x32x16_f16(al, bh[kt], acc2[mt], 0, 0, 0);
      }
    }
    // cnorm K-extension: acc += cn1, acc2 += (cn2s + cn3s)
#pragma unroll
    for (int mt = 0; mt < 4; ++mt) {
      int c = ph * 128 + mt * 32 + col;
      int off = hl ? 2048 : c * 8;
      f16x8 aeh = *reinterpret_cast<const f16x8*>(&exh[off]);
      f16x8 ael = *reinterpret_cast<const f16x8*>(&exl[off]);
      acc[mt] = __builtin_amdgcn_mfma_f32_32x32x16_f16(aeh, beh, acc[mt], 0, 0, 0);
      acc2[mt] = __builtin_amdgcn_mfma_f32_32x32x16_f16(ael, beh, acc2[mt], 0, 0, 0);
    }
    // argmin epilogue: dist = acc + acc2/4096  (= ||c||^2 - 2 k.c)
#pragma unroll
    for (int mt = 0; mt < 4; ++mt) {
#pragma unroll
      for (int r = 0; r < 16; ++r) {
        float dv = fmaf(acc2[mt][r], LO_INV, acc[mt][r]);
        int cc = ph * 128 + mt * 32 + (r & 3) + 8 * (r >> 2) + 4 * hl;
        if (dv < bestd || (dv == bestd && cc < bestc)) { bestd = dv; bestc = cc; }
      }
    }
  }

  // merge the two k-half lanes (rows 0-3,8-11,... vs 4-7,12-15,...)
  float od = __shfl_xor(bestd, 32, 64);
  int oc = __shfl_xor(bestc, 32, 64);
  if (od < bestd || (od == bestd && oc < bestc)) { bestd = od; bestc = oc; }

  if (hl == 0) {
    out_idx[pt] = (float)bestc;
    atomicAdd(&hist[bestc], 1u);
  }
  __syncthreads();
  if (tid < K) {
    unsigned int h = hist[tid];
    if (h) atomicAdd(&counts[tid], h);
  }
}

// ---------------- segment sums: LDS ds_add_f32, flush via HW global fp32 atomics ----
__global__ __launch_bounds__(1024) void k_psum(const float* __restrict__ src,
                                               const float* __restrict__ idxf,
                                               float* __restrict__ gacc, int ppb) {
  __shared__ float acc[K * D];  // 128 KB
  for (int i = threadIdx.x; i < K * D; i += 1024) acc[i] = 0.f;
  __syncthreads();

  const int d = threadIdx.x & 127;
  const int ps = threadIdx.x >> 7;  // 8 points in flight per 128-thread group
  const int base = blockIdx.x * ppb;

#pragma unroll 4
  for (int p = ps; p < ppb; p += 8) {
    int c = (int)idxf[base + p];
    float v = src[(size_t)(base + p) * D + d];
    unsafeAtomicAdd(&acc[(c << 7) + d], v);  // ds_add_f32 (wave-uniform c)
  }
  __syncthreads();

  for (int i = threadIdx.x; i < K * D; i += 1024) {
    float v = acc[i];
    if (v != 0.f) unsafeAtomicAdd(&gacc[i], v);  // global_atomic_add_f32
  }
}

// ---------------- EMA update + counts ----------------
__global__ __launch_bounds__(256) void k_finish(
    const float* __restrict__ ksum, const float* __restrict__ vsum,
    const float* __restrict__ kc, const float* __restrict__ vc,
    const float* __restrict__ oldcnt, const unsigned int* __restrict__ counts,
    float* __restrict__ ok, float* __restrict__ ov, float* __restrict__ ocnt) {
  int i = blockIdx.x * 256 + threadIdx.x;  // 0..K*D-1
  int c = i >> 7;
  float cnt = (float)counts[c];
  float safe = fmaxf(cnt, 1.0f);
  float km = ksum[i] / safe, vm = vsum[i] / safe;
  float okc = kc[i], ovc = vc[i];
  bool ne = cnt > 0.f;
  ok[i] = ne ? (1.0f - LR) * okc + LR * km : okc;
  ov[i] = ne ? (1.0f - LR) * ovc + LR * vm : ovc;
  if ((i & 127) == 0) ocnt[c] = oldcnt[c] + cnt;
}

extern "C" void kernel_launch(void* const* d_in, const int* in_sizes, int n_in,
                              void* d_out, int out_size, void* d_ws, size_t ws_size,
                              hipStream_t stream) {
  const float* keys = (const float*)d_in[0];
  const float* values = (const float*)d_in[1];
  const float* kcent = (const float*)d_in[2];
  const float* vcent = (const float*)d_in[3];
  const float* oldcnt = (const float*)d_in[4];
  const int N = in_sizes[0] / D;  // 262144

  float* ws = (float*)d_ws;
  unsigned int* w_counts = (unsigned int*)ws;        // 256
  float* w_ksum = ws + 256;                          // 32768
  float* w_vsum = ws + 256 + K * D;                  // 32768
  _Float16* w_csplit = (_Float16*)(ws + 256 + 2 * K * D);  // 65536 halves
  _Float16* w_extH = w_csplit + 65536;               // 2048 halves
  _Float16* w_extL = w_extH + 2048;                  // 2048 halves

  float* o_idx = (float*)d_out;  // N
  float* o_kc = o_idx + N;       // K*D
  float* o_vc = o_kc + K * D;    // K*D
  float* o_cnt = o_vc + K * D;   // K

  int zn = 256 + 2 * K * D;
  k_zero<<<(zn + 255) / 256, 256, 0, stream>>>(ws, zn);
  k_prep<<<K, 128, 0, stream>>>(kcent, w_csplit, w_extH, w_extL);
  k_assign<<<N / 256, 512, 0, stream>>>(keys, w_csplit, w_extH, w_extL, o_idx,
                                        w_counts);
  int ppb = N / 256;  // 1024 points per psum block
  k_psum<<<256, 1024, 0, stream>>>(keys, o_idx, w_ksum, ppb);
  k_psum<<<256, 1024, 0, stream>>>(values, o_idx, w_vsum, ppb);
  k_finish<<<(K * D) / 256, 256, 0, stream>>>(w_ksum, w_vsum, kcent, vcent, oldcnt,
                                              w_counts, o_kc, o_vc, o_cnt);
}